// Round 5
// baseline (343.487 us; speedup 1.0000x reference)
//
#include <hip/hip_runtime.h>
#include <cfloat>

#define BB   32
#define VV   2048
#define KNB  40
#define FIN  64
#define DD   4
#define PP   64
#define NN   (BB*VV)           // 65536

static __device__ __forceinline__ float fast_tanh(float z) {
    z = fminf(fmaxf(z, -15.f), 15.f);
    float e = __expf(2.f * z);
    return (e - 1.f) / (e + 1.f);
}

// Wave64 inclusive add-scan via DPP (rocPRIM pattern): 6 VALU ops, no DS pipe.
static __device__ __forceinline__ int wave_incl_scan(int x) {
    x += __builtin_amdgcn_update_dpp(0, x, 0x111, 0xf, 0xf, true); // row_shr:1
    x += __builtin_amdgcn_update_dpp(0, x, 0x112, 0xf, 0xf, true); // row_shr:2
    x += __builtin_amdgcn_update_dpp(0, x, 0x114, 0xf, 0xf, true); // row_shr:4
    x += __builtin_amdgcn_update_dpp(0, x, 0x118, 0xf, 0xf, true); // row_shr:8
    x += __builtin_amdgcn_update_dpp(0, x, 0x142, 0xa, 0xf, true); // row_bcast:15 -> rows 1,3
    x += __builtin_amdgcn_update_dpp(0, x, 0x143, 0xc, 0xf, true); // row_bcast:31 -> rows 2,3
    return x;
}

// ---------------------------------------------------------------------------
// Kernel 1: coords = x@W_s + b_s (N x 4), feats = x@W_f + b_f (N x 64)
// (unchanged, passing)
// ---------------------------------------------------------------------------
__global__ __launch_bounds__(256) void k_embed(
    const float* __restrict__ x, const float* __restrict__ Ws,
    const float* __restrict__ bs, const float* __restrict__ Wf,
    const float* __restrict__ bf, float* __restrict__ coords,
    float* __restrict__ feats)
{
    __shared__ float Xs[64][68];
    __shared__ float Wfs[64][64];
    __shared__ float Wss[64][4];
    const int tid  = threadIdx.x;
    const int row0 = blockIdx.x * 64;

    #pragma unroll
    for (int i = 0; i < 4; ++i) {
        const int idx = tid + i * 256;
        const int r   = idx >> 4;
        const int k4  = (idx & 15) << 2;
        float4 v = *(const float4*)(x + (size_t)(row0 + r) * FIN + k4);
        Xs[k4+0][r] = v.x; Xs[k4+1][r] = v.y; Xs[k4+2][r] = v.z; Xs[k4+3][r] = v.w;
        ((float4*)Wfs)[idx] = ((const float4*)Wf)[idx];
    }
    if (tid < 64) *(float4*)Wss[tid] = ((const float4*)Ws)[tid];
    __syncthreads();

    const int tx = tid & 15;
    const int ty = tid >> 4;
    float acc[4][4] = {};
    #pragma unroll 16
    for (int k = 0; k < 64; ++k) {
        float4 a = *(const float4*)&Xs[k][ty * 4];
        float4 b = *(const float4*)&Wfs[k][tx * 4];
        acc[0][0] += a.x*b.x; acc[0][1] += a.x*b.y; acc[0][2] += a.x*b.z; acc[0][3] += a.x*b.w;
        acc[1][0] += a.y*b.x; acc[1][1] += a.y*b.y; acc[1][2] += a.y*b.z; acc[1][3] += a.y*b.w;
        acc[2][0] += a.z*b.x; acc[2][1] += a.z*b.y; acc[2][2] += a.z*b.z; acc[2][3] += a.z*b.w;
        acc[3][0] += a.w*b.x; acc[3][1] += a.w*b.y; acc[3][2] += a.w*b.z; acc[3][3] += a.w*b.w;
    }
    const float4 bfv = *(const float4*)(bf + tx * 4);
    const float ar[4] = {bfv.x, bfv.y, bfv.z, bfv.w};
    #pragma unroll
    for (int i = 0; i < 4; ++i) {
        float4 o = { acc[i][0] + ar[0], acc[i][1] + ar[1],
                     acc[i][2] + ar[2], acc[i][3] + ar[3] };
        *(float4*)(feats + (size_t)(row0 + ty * 4 + i) * PP + tx * 4) = o;
    }

    const int cr = tid >> 2, cc = tid & 3;
    float ca = bs[cc];
    #pragma unroll 16
    for (int k = 0; k < 64; ++k) ca += Xs[k][cr] * Wss[k][cc];
    coords[(size_t)(row0 + cr) * DD + cc] = ca;
}

// ---------------------------------------------------------------------------
// Kernel 2a: k_select — top-40 KNN selection only.
// R5: k_knn split in two. Rationale: 4 structurally different fused kernels
// all pinned at ~221us with Occupancy 21% -> per-row serial chain is the
// limiter, and fusing the gather/pool forced its vmcnt drain + fv[40] regs
// into the same chain. Select semantics BIT-IDENTICAL to passing R4
// (256 bins, width 1/64, same tie policy). Output: 40 packed u32 per row
// written into the row's `collected` slot (consumed then overwritten by
// k_pool — zero extra workspace):
//   u32 = (idx:11b << 20) | (f32_bits(exp(-10*d2)) >> 11)   [12-bit mantissa]
// ---------------------------------------------------------------------------
__global__ __launch_bounds__(256) void k_select(
    const float* __restrict__ coords, float* __restrict__ collected)
{
    __shared__ int    hist[4][256];       // 4 KB  (per-wave)
    __shared__ float2 candP[4][KNB];      // 1.25 KB (per-wave): (d2, idx)

    const int tid   = threadIdx.x;
    const int lane  = tid & 63;
    const int w     = tid >> 6;
    // XCD swizzle: 4096 blocks, 8 XCDs -> 512 contiguous blocks per XCD.
    const int bid   = (int)blockIdx.x;
    const int swz   = ((bid & 7) << 9) + (bid >> 3);
    const int batch = swz >> 7;            // 128 blocks of 16 rows per batch
    const int chunk = swz & 127;
    const float4* cb4 = (const float4*)(coords + (size_t)batch * VV * DD);

    const int4 izero = {0, 0, 0, 0};

    for (int rr = 0; rr < 4; ++rr) {
        // v is wave-uniform; make it provably so for the compiler.
        const int vu = __builtin_amdgcn_readfirstlane((chunk << 4) + (w << 2) + rr);
        const float4 cv = cb4[vu];               // uniform -> scalar load
        const int jself = vu >> 6;
        const int lself = vu & 63;

        // ---- fused distance + attempt-0 histogram ([0,4), 256 bins) ----
        ((int4*)hist[w])[lane] = izero;
        float d2loc[32];
        #pragma unroll
        for (int j = 0; j < 32; ++j) {
            const float4 cw = cb4[lane + (j << 6)];
            const float dx = cv.x - cw.x, dy = cv.y - cw.y;
            const float dz = cv.z - cw.z, dw = cv.w - cw.w;
            float d2 = dx*dx + dy*dy + dz*dz + dw*dw;
            if (j == jself && lane == lself) d2 = FLT_MAX;  // self -> sentinel
            d2loc[j] = d2;
            if (d2 < 4.f)
                atomicAdd(&hist[w][(int)(d2 * 64.f)], 1);   // exact pow2 scale
        }

        float rscale = 0.015625f;              // bin width (attempt 0: 1/64)
        int4 hv = ((const int4*)hist[w])[lane];
        int local = hv.x + hv.y + hv.z + hv.w;
        int incl  = wave_incl_scan(local);
        const int total = __builtin_amdgcn_readlane(incl, 63);
        if (total < KNB) {                     // rare fallback: [0,1024), width 4
            rscale = 4.f;
            ((int4*)hist[w])[lane] = izero;
            #pragma unroll
            for (int j = 0; j < 32; ++j) {
                const float d2 = d2loc[j];
                if (d2 < 1024.f)
                    atomicAdd(&hist[w][(int)(d2 * 0.25f)], 1);
            }
            hv = ((const int4*)hist[w])[lane];
            local = hv.x + hv.y + hv.z + hv.w;
            incl  = wave_incl_scan(local);
        }
        const int excl = incl - local;
        const bool pred = (excl < KNB) && (incl >= KNB);
        const unsigned long long m = __ballot(pred);
        const int src = (m == 0ull) ? 0 : ((int)__ffsll(m) - 1);  // uniform
        int gg = 0, nnb = 0;
        if (pred) {
            const int hh[4] = {hv.x, hv.y, hv.z, hv.w};
            int cacc = excl, found = -1;
            #pragma unroll
            for (int q = 0; q < 4; ++q) {
                if (found < 0 && cacc + hh[q] >= KNB) { found = q; nnb = cacc; }
                cacc += hh[q];
            }
            gg = (lane << 2) + found;
        }
        const int g1  = __builtin_amdgcn_readlane(gg,  src);
        const int nb1 = __builtin_amdgcn_readlane(nnb, src);
        // (int)(d2*scale) < g1  <=>  d2 < g1*rscale (exact: pow2, d2>=0)
        const float flo = (float)g1 * rscale;
        const float fhi = (float)(g1 + 1) * rscale;

        // ---- collect: masks + packed scan + ONE predicated write per j ----
        unsigned int maskA = 0u, maskB = 0u;   // A: d2<flo, B: boundary bin
        #pragma unroll
        for (int j = 0; j < 32; ++j) {
            const float d2 = d2loc[j];
            if (d2 < flo) maskA |= (1u << j);
            else if (d2 < fhi) maskB |= (1u << j);
        }
        const int packed = __popc(maskA) | (__popc(maskB) << 16);
        const int incl2  = wave_incl_scan(packed);
        const int excl2  = incl2 - packed;
        int baseA = excl2 & 0xFFFF;            // region A: [0, nb1)
        int baseB = nb1 + (excl2 >> 16);       // region B: [nb1, 40), capped
        #pragma unroll
        for (int j = 0; j < 32; ++j) {
            const float d2 = d2loc[j];
            const bool a = (d2 < flo);
            const bool s = (d2 < fhi);          // a || boundary
            const bool b = s && !a;
            const int  dst = a ? baseA : baseB;
            if (s && (a || baseB < KNB))
                candP[w][dst] = make_float2(d2, __int_as_float(lane + (j << 6)));
            baseA += (int)a;
            baseB += (int)b;
        }

        // ---- lanes 0..39: weight + pack + coalesced write to row slot ----
        if (lane < KNB) {
            const float2 p = candP[w][lane];
            const int   idx = __float_as_int(p.y);
            const float wgt = __expf(-10.f * p.x);          // wgt in [0,1]
            const unsigned int u =
                ((unsigned int)idx << 20) | (__float_as_uint(wgt) >> 11);
            unsigned int* rowp =
                (unsigned int*)(collected + ((size_t)(batch * VV + vu) << 7));
            rowp[lane] = u;
        }
    }
}

// ---------------------------------------------------------------------------
// Kernel 2b: k_pool — gather 40 neighbor feature rows, weighted max/mean.
// One wave per row (4 rows/block). Packed candidates read into registers,
// decoded via readlane -> SGPR (SALU decode), saddr gathers in two 20-deep
// chunks, then the row slot is overwritten with the pooled output.
// Low VGPR -> high occupancy; thousands of independent rows hide latency.
// ---------------------------------------------------------------------------
__global__ __launch_bounds__(256) void k_pool(
    const float* __restrict__ feats, float* __restrict__ collected)
{
    const int tid  = threadIdx.x;
    const int lane = tid & 63;
    const int w4   = tid >> 6;             // wave in block: 0..3
    // XCD swizzle: 16384 blocks, 8 XCDs -> 2048 contiguous blocks per XCD.
    const int bid  = (int)blockIdx.x;
    const int swz  = ((bid & 7) << 11) + (bid >> 3);
    const int v    = (swz << 2) + w4;      // global row
    const int batch = v >> 11;
    const float* fb = feats + (size_t)batch * VV * PP;
    float* rowp = collected + ((size_t)v << 7);

    // read packed candidates (lanes 0..39) — consumed before rowp overwrite
    unsigned int u = 0u;
    if (lane < KNB) u = ((const unsigned int*)rowp)[lane];

    float mx = -FLT_MAX, sm = 0.f;
    #pragma unroll
    for (int j0 = 0; j0 < KNB; j0 += 20) {
        float fv[20]; float wv[20];
        #pragma unroll
        for (int t = 0; t < 20; ++t) {
            const unsigned int su =
                (unsigned int)__builtin_amdgcn_readlane((int)u, j0 + t); // SGPR
            const int si = (int)(su >> 20);                               // SALU
            wv[t] = __uint_as_float((su & 0xFFFFFu) << 11);               // SALU
            fv[t] = fb[(size_t)(si * PP) + lane];                         // saddr
        }
        #pragma unroll
        for (int t = 0; t < 20; ++t) {
            const float nv = fv[t] * wv[t];
            mx = fmaxf(mx, nv);
            sm += nv;
        }
    }
    rowp[lane]      = mx;
    rowp[PP + lane] = sm * (1.f / KNB);
}

// ---------------------------------------------------------------------------
// Kernel 3: out = tanh(concat(x, collected) @ W_out + b_out), (N x 192)@(192 x 128)
// (unchanged, passing)
// ---------------------------------------------------------------------------
__global__ __launch_bounds__(256) void k_out(
    const float* __restrict__ x, const float* __restrict__ collected,
    const float* __restrict__ Wout, const float* __restrict__ bout,
    float* __restrict__ out)
{
    __shared__ float As[16][68];   // [kk][r], +4 pad
    __shared__ float Bs[16][128];
    const int tid = threadIdx.x;
    const int tx  = tid & 15;
    const int ty  = tid >> 4;
    const int row0 = blockIdx.x * 64;

    float acc[4][8];
    #pragma unroll
    for (int i = 0; i < 4; ++i)
        #pragma unroll
        for (int j = 0; j < 8; ++j) acc[i][j] = 0.f;

    for (int k0 = 0; k0 < 192; k0 += 16) {
        {   // stage A tile transposed: thread loads (r, kk4..kk4+3), scatters
            const int r   = tid >> 2;
            const int kk4 = (tid & 3) << 2;
            const float* src = (k0 < 64)
                ? (x + (size_t)(row0 + r) * FIN + (k0 + kk4))
                : (collected + (size_t)(row0 + r) * 128 + (k0 - 64 + kk4));
            float4 v = *(const float4*)src;
            As[kk4+0][r] = v.x; As[kk4+1][r] = v.y;
            As[kk4+2][r] = v.z; As[kk4+3][r] = v.w;
        }
        #pragma unroll
        for (int rep = 0; rep < 2; ++rep) {
            const int e = (tid + rep * 256) * 4;
            const int kk = e >> 7, c = e & 127;
            *(float4*)&Bs[kk][c] = *(const float4*)(Wout + (size_t)(k0 + kk) * 128 + c);
        }
        __syncthreads();
        #pragma unroll
        for (int kk = 0; kk < 16; ++kk) {
            float4 a  = *(const float4*)&As[kk][ty * 4];
            float4 b0 = *(const float4*)&Bs[kk][tx * 4];
            float4 b1 = *(const float4*)&Bs[kk][64 + tx * 4];
            const float av[4] = {a.x, a.y, a.z, a.w};
            #pragma unroll
            for (int i = 0; i < 4; ++i) {
                acc[i][0] += av[i] * b0.x; acc[i][1] += av[i] * b0.y;
                acc[i][2] += av[i] * b0.z; acc[i][3] += av[i] * b0.w;
                acc[i][4] += av[i] * b1.x; acc[i][5] += av[i] * b1.y;
                acc[i][6] += av[i] * b1.z; acc[i][7] += av[i] * b1.w;
            }
        }
        __syncthreads();
    }

    #pragma unroll
    for (int i = 0; i < 4; ++i) {
        const int row = row0 + ty * 4 + i;
        float4 o0, o1;
        o0.x = fast_tanh(acc[i][0] + bout[tx*4+0]);
        o0.y = fast_tanh(acc[i][1] + bout[tx*4+1]);
        o0.z = fast_tanh(acc[i][2] + bout[tx*4+2]);
        o0.w = fast_tanh(acc[i][3] + bout[tx*4+3]);
        o1.x = fast_tanh(acc[i][4] + bout[64+tx*4+0]);
        o1.y = fast_tanh(acc[i][5] + bout[64+tx*4+1]);
        o1.z = fast_tanh(acc[i][6] + bout[64+tx*4+2]);
        o1.w = fast_tanh(acc[i][7] + bout[64+tx*4+3]);
        *(float4*)(out + (size_t)row * 128 + tx * 4)      = o0;
        *(float4*)(out + (size_t)row * 128 + 64 + tx * 4) = o1;
    }
}

// ---------------------------------------------------------------------------
extern "C" void kernel_launch(void* const* d_in, const int* in_sizes, int n_in,
                              void* d_out, int out_size, void* d_ws, size_t ws_size,
                              hipStream_t stream)
{
    const float* x    = (const float*)d_in[0];
    // d_in[1] = row_splits: uniform arange(B+1)*V — fixed structure, unused.
    const float* Ws   = (const float*)d_in[2];
    const float* bs   = (const float*)d_in[3];
    const float* Wf   = (const float*)d_in[4];
    const float* bf   = (const float*)d_in[5];
    const float* Wout = (const float*)d_in[6];
    const float* bout = (const float*)d_in[7];
    float* out = (float*)d_out;

    float* coords = (float*)d_ws;                                            // 1 MB
    float* feats  = (float*)((char*)d_ws + (size_t)NN * DD * sizeof(float)); // 16 MB
    float* collected = out;   // reuse d_out as scratch for pooled features

    hipLaunchKernelGGL(k_embed, dim3(NN / 64), dim3(256), 0, stream,
                       x, Ws, bs, Wf, bf, coords, feats);
    // selection: 16 rows per block (4 waves x 4 rows) -> 4096 blocks
    hipLaunchKernelGGL(k_select, dim3(NN / 16), dim3(256), 0, stream,
                       coords, collected);
    // pooling: 1 row per wave, 4 waves/block -> 16384 blocks
    hipLaunchKernelGGL(k_pool, dim3(NN / 4), dim3(256), 0, stream,
                       feats, collected);
    hipLaunchKernelGGL(k_out, dim3(NN / 64), dim3(256), 0, stream,
                       x, collected, Wout, bout, out);
}

// Round 6
// 317.337 us; speedup vs baseline: 1.0824x; 1.0824x over previous
//
#include <hip/hip_runtime.h>
#include <cfloat>

#define BB   32
#define VV   2048
#define KNB  40
#define FIN  64
#define DD   4
#define PP   64
#define NN   (BB*VV)           // 65536

static __device__ __forceinline__ float fast_tanh(float z) {
    z = fminf(fmaxf(z, -15.f), 15.f);
    float e = __expf(2.f * z);
    return (e - 1.f) / (e + 1.f);
}

// Wave64 inclusive add-scan via DPP (rocPRIM pattern): 6 VALU ops, no DS pipe.
static __device__ __forceinline__ int wave_incl_scan(int x) {
    x += __builtin_amdgcn_update_dpp(0, x, 0x111, 0xf, 0xf, true); // row_shr:1
    x += __builtin_amdgcn_update_dpp(0, x, 0x112, 0xf, 0xf, true); // row_shr:2
    x += __builtin_amdgcn_update_dpp(0, x, 0x114, 0xf, 0xf, true); // row_shr:4
    x += __builtin_amdgcn_update_dpp(0, x, 0x118, 0xf, 0xf, true); // row_shr:8
    x += __builtin_amdgcn_update_dpp(0, x, 0x142, 0xa, 0xf, true); // row_bcast:15 -> rows 1,3
    x += __builtin_amdgcn_update_dpp(0, x, 0x143, 0xc, 0xf, true); // row_bcast:31 -> rows 2,3
    return x;
}

// ---------------------------------------------------------------------------
// Kernel 1: coords = x@W_s + b_s (N x 4), feats = x@W_f + b_f (N x 64)
// (unchanged, passing)
// ---------------------------------------------------------------------------
__global__ __launch_bounds__(256) void k_embed(
    const float* __restrict__ x, const float* __restrict__ Ws,
    const float* __restrict__ bs, const float* __restrict__ Wf,
    const float* __restrict__ bf, float* __restrict__ coords,
    float* __restrict__ feats)
{
    __shared__ float Xs[64][68];
    __shared__ float Wfs[64][64];
    __shared__ float Wss[64][4];
    const int tid  = threadIdx.x;
    const int row0 = blockIdx.x * 64;

    #pragma unroll
    for (int i = 0; i < 4; ++i) {
        const int idx = tid + i * 256;
        const int r   = idx >> 4;
        const int k4  = (idx & 15) << 2;
        float4 v = *(const float4*)(x + (size_t)(row0 + r) * FIN + k4);
        Xs[k4+0][r] = v.x; Xs[k4+1][r] = v.y; Xs[k4+2][r] = v.z; Xs[k4+3][r] = v.w;
        ((float4*)Wfs)[idx] = ((const float4*)Wf)[idx];
    }
    if (tid < 64) *(float4*)Wss[tid] = ((const float4*)Ws)[tid];
    __syncthreads();

    const int tx = tid & 15;
    const int ty = tid >> 4;
    float acc[4][4] = {};
    #pragma unroll 16
    for (int k = 0; k < 64; ++k) {
        float4 a = *(const float4*)&Xs[k][ty * 4];
        float4 b = *(const float4*)&Wfs[k][tx * 4];
        acc[0][0] += a.x*b.x; acc[0][1] += a.x*b.y; acc[0][2] += a.x*b.z; acc[0][3] += a.x*b.w;
        acc[1][0] += a.y*b.x; acc[1][1] += a.y*b.y; acc[1][2] += a.y*b.z; acc[1][3] += a.y*b.w;
        acc[2][0] += a.z*b.x; acc[2][1] += a.z*b.y; acc[2][2] += a.z*b.z; acc[2][3] += a.z*b.w;
        acc[3][0] += a.w*b.x; acc[3][1] += a.w*b.y; acc[3][2] += a.w*b.z; acc[3][3] += a.w*b.w;
    }
    const float4 bfv = *(const float4*)(bf + tx * 4);
    const float ar[4] = {bfv.x, bfv.y, bfv.z, bfv.w};
    #pragma unroll
    for (int i = 0; i < 4; ++i) {
        float4 o = { acc[i][0] + ar[0], acc[i][1] + ar[1],
                     acc[i][2] + ar[2], acc[i][3] + ar[3] };
        *(float4*)(feats + (size_t)(row0 + ty * 4 + i) * PP + tx * 4) = o;
    }

    const int cr = tid >> 2, cc = tid & 3;
    float ca = bs[cc];
    #pragma unroll 16
    for (int k = 0; k < 64; ++k) ca += Xs[k][cr] * Wss[k][cc];
    coords[(size_t)(row0 + cr) * DD + cc] = ca;
}

// ---------------------------------------------------------------------------
// select_row: 256-bin select + collect for one row (semantics verbatim from
// passing R4/R5: same FP ops, same tie policy). d2 array stays in registers
// (inlined, static indices). Results land in candP[0..KNB).
// ---------------------------------------------------------------------------
static __device__ __forceinline__ void select_row(
    const float (&d2loc)[32], int* __restrict__ hw,
    float2* __restrict__ cp, const int lane)
{
    const int4 izero = {0, 0, 0, 0};
    float rscale = 0.015625f;              // bin width (attempt 0: 1/64)
    int4 hv = ((const int4*)hw)[lane];
    int local = hv.x + hv.y + hv.z + hv.w;
    int incl  = wave_incl_scan(local);
    const int total = __builtin_amdgcn_readlane(incl, 63);
    if (total < KNB) {                     // rare fallback: [0,1024), width 4
        rscale = 4.f;
        ((int4*)hw)[lane] = izero;
        #pragma unroll
        for (int j = 0; j < 32; ++j) {
            const float d2 = d2loc[j];
            if (d2 < 1024.f)
                atomicAdd(&hw[(int)(d2 * 0.25f)], 1);
        }
        hv = ((const int4*)hw)[lane];
        local = hv.x + hv.y + hv.z + hv.w;
        incl  = wave_incl_scan(local);
    }
    const int excl = incl - local;
    const bool pred = (excl < KNB) && (incl >= KNB);
    const unsigned long long m = __ballot(pred);
    const int src = (m == 0ull) ? 0 : ((int)__ffsll(m) - 1);  // uniform
    int gg = 0, nnb = 0;
    if (pred) {
        const int hh[4] = {hv.x, hv.y, hv.z, hv.w};
        int cacc = excl, found = -1;
        #pragma unroll
        for (int q = 0; q < 4; ++q) {
            if (found < 0 && cacc + hh[q] >= KNB) { found = q; nnb = cacc; }
            cacc += hh[q];
        }
        gg = (lane << 2) + found;
    }
    const int g1  = __builtin_amdgcn_readlane(gg,  src);
    const int nb1 = __builtin_amdgcn_readlane(nnb, src);
    // (int)(d2*scale) < g1  <=>  d2 < g1*rscale (exact: pow2, d2>=0)
    const float flo = (float)g1 * rscale;
    const float fhi = (float)(g1 + 1) * rscale;

    // ---- collect: masks + packed scan + ONE predicated write per j ----
    unsigned int maskA = 0u, maskB = 0u;   // A: d2<flo, B: boundary bin
    #pragma unroll
    for (int j = 0; j < 32; ++j) {
        const float d2 = d2loc[j];
        if (d2 < flo) maskA |= (1u << j);
        else if (d2 < fhi) maskB |= (1u << j);
    }
    const int packed = __popc(maskA) | (__popc(maskB) << 16);
    const int incl2  = wave_incl_scan(packed);
    const int excl2  = incl2 - packed;
    int baseA = excl2 & 0xFFFF;            // region A: [0, nb1)
    int baseB = nb1 + (excl2 >> 16);       // region B: [nb1, 40), capped
    #pragma unroll
    for (int j = 0; j < 32; ++j) {
        const float d2 = d2loc[j];
        const bool a = (d2 < flo);
        const bool s = (d2 < fhi);          // a || boundary
        const bool b = s && !a;
        const int  dst = a ? baseA : baseB;
        if (s && (a || baseB < KNB))
            cp[dst] = make_float2(d2, __int_as_float(lane + (j << 6)));
        baseA += (int)a;
        baseB += (int)b;
    }
}

// ---------------------------------------------------------------------------
// Kernel 2a: k_select — top-40 KNN selection, TWO rows per wave.
// R6: five structurally different kernels pinned at ~193-223us with every
// pipe half-idle -> per-row serial chain + capped residency (VGPR<=128 tier
// = 16 waves/CU) is the limiter. Fix: in-wave ILP. One fused distance loop
// loads each candidate coord ONCE and feeds two independent rows (d2A,d2B,
// two hist buffers); the two select/collect phases interleave so row B's DS
// latency hides under row A's VALU. Selection math verbatim from R4/R5.
// __launch_bounds__(256,4) pins VGPR<=128 (stay in 16-waves/CU tier).
// Output: 40 packed u32 per row into the row's `collected` slot:
//   u32 = (idx:11b << 20) | (f32_bits(exp(-10*d2)) >> 11)
// ---------------------------------------------------------------------------
__global__ __launch_bounds__(256, 4) void k_select(
    const float* __restrict__ coords, float* __restrict__ collected)
{
    __shared__ int    hist[4][2][256];    // 8 KB  (per-wave x 2 rows)
    __shared__ float2 candP[4][2][KNB];   // 2.5 KB

    const int tid   = threadIdx.x;
    const int lane  = tid & 63;
    const int w     = tid >> 6;
    // XCD swizzle: 8192 blocks, 8 XCDs -> 1024 contiguous blocks per XCD.
    const int bid   = (int)blockIdx.x;
    const int swz   = ((bid & 7) << 10) + (bid >> 3);
    const int batch = swz >> 8;            // 256 blocks of 8 rows per batch
    const int chunk = swz & 255;
    const float4* cb4 = (const float4*)(coords + (size_t)batch * VV * DD);

    const int4 izero = {0, 0, 0, 0};

    // two rows per wave: vA even, vB = vA+1 (both wave-uniform)
    const int vA = __builtin_amdgcn_readfirstlane((chunk << 3) + (w << 1));
    const int vB = vA + 1;
    const float4 cvA = cb4[vA];            // uniform -> scalar loads
    const float4 cvB = cb4[vB];
    const int jself  = vA >> 6;            // == vB >> 6 (vA even, &63 < 63)
    const int lselfA = vA & 63;
    const int lselfB = lselfA + 1;

    ((int4*)hist[w][0])[lane] = izero;
    ((int4*)hist[w][1])[lane] = izero;

    // ---- fused distance + histogram for BOTH rows (cw loaded once) ----
    float dA[32], dB[32];
    #pragma unroll
    for (int j = 0; j < 32; ++j) {
        const float4 cw = cb4[lane + (j << 6)];
        const float dxA = cvA.x - cw.x, dyA = cvA.y - cw.y;
        const float dzA = cvA.z - cw.z, dwA = cvA.w - cw.w;
        float d2A = dxA*dxA + dyA*dyA + dzA*dzA + dwA*dwA;
        const float dxB = cvB.x - cw.x, dyB = cvB.y - cw.y;
        const float dzB = cvB.z - cw.z, dwB = cvB.w - cw.w;
        float d2B = dxB*dxB + dyB*dyB + dzB*dzB + dwB*dwB;
        if (j == jself) {                  // uniform scalar branch
            if (lane == lselfA) d2A = FLT_MAX;
            if (lane == lselfB) d2B = FLT_MAX;
        }
        dA[j] = d2A; dB[j] = d2B;
        if (d2A < 4.f) atomicAdd(&hist[w][0][(int)(d2A * 64.f)], 1);
        if (d2B < 4.f) atomicAdd(&hist[w][1][(int)(d2B * 64.f)], 1);
    }

    // ---- per-row select + collect (compiler interleaves the two) ----
    select_row(dA, hist[w][0], candP[w][0], lane);
    select_row(dB, hist[w][1], candP[w][1], lane);

    // ---- lanes 0..39: weight + pack + coalesced write to both row slots ----
    if (lane < KNB) {
        const float2 p0 = candP[w][0][lane];
        const float2 p1 = candP[w][1][lane];
        const unsigned int u0 =
            ((unsigned int)__float_as_int(p0.y) << 20) |
            (__float_as_uint(__expf(-10.f * p0.x)) >> 11);
        const unsigned int u1 =
            ((unsigned int)__float_as_int(p1.y) << 20) |
            (__float_as_uint(__expf(-10.f * p1.x)) >> 11);
        unsigned int* rowpA =
            (unsigned int*)(collected + ((size_t)(batch * VV + vA) << 7));
        rowpA[lane]       = u0;
        rowpA[128 + lane] = u1;            // row vB = vA+1: +128 floats
    }
}

// ---------------------------------------------------------------------------
// Kernel 2b: k_pool — gather 40 neighbor feature rows, weighted max/mean.
// (unchanged from R5, passing)
// ---------------------------------------------------------------------------
__global__ __launch_bounds__(256) void k_pool(
    const float* __restrict__ feats, float* __restrict__ collected)
{
    const int tid  = threadIdx.x;
    const int lane = tid & 63;
    const int w4   = tid >> 6;             // wave in block: 0..3
    // XCD swizzle: 16384 blocks, 8 XCDs -> 2048 contiguous blocks per XCD.
    const int bid  = (int)blockIdx.x;
    const int swz  = ((bid & 7) << 11) + (bid >> 3);
    const int v    = (swz << 2) + w4;      // global row
    const int batch = v >> 11;
    const float* fb = feats + (size_t)batch * VV * PP;
    float* rowp = collected + ((size_t)v << 7);

    // read packed candidates (lanes 0..39) — consumed before rowp overwrite
    unsigned int u = 0u;
    if (lane < KNB) u = ((const unsigned int*)rowp)[lane];

    float mx = -FLT_MAX, sm = 0.f;
    #pragma unroll
    for (int j0 = 0; j0 < KNB; j0 += 20) {
        float fv[20]; float wv[20];
        #pragma unroll
        for (int t = 0; t < 20; ++t) {
            const unsigned int su =
                (unsigned int)__builtin_amdgcn_readlane((int)u, j0 + t); // SGPR
            const int si = (int)(su >> 20);                               // SALU
            wv[t] = __uint_as_float((su & 0xFFFFFu) << 11);               // SALU
            fv[t] = fb[(size_t)(si * PP) + lane];                         // saddr
        }
        #pragma unroll
        for (int t = 0; t < 20; ++t) {
            const float nv = fv[t] * wv[t];
            mx = fmaxf(mx, nv);
            sm += nv;
        }
    }
    rowp[lane]      = mx;
    rowp[PP + lane] = sm * (1.f / KNB);
}

// ---------------------------------------------------------------------------
// Kernel 3: out = tanh(concat(x, collected) @ W_out + b_out), (N x 192)@(192 x 128)
// (unchanged, passing)
// ---------------------------------------------------------------------------
__global__ __launch_bounds__(256) void k_out(
    const float* __restrict__ x, const float* __restrict__ collected,
    const float* __restrict__ Wout, const float* __restrict__ bout,
    float* __restrict__ out)
{
    __shared__ float As[16][68];   // [kk][r], +4 pad
    __shared__ float Bs[16][128];
    const int tid = threadIdx.x;
    const int tx  = tid & 15;
    const int ty  = tid >> 4;
    const int row0 = blockIdx.x * 64;

    float acc[4][8];
    #pragma unroll
    for (int i = 0; i < 4; ++i)
        #pragma unroll
        for (int j = 0; j < 8; ++j) acc[i][j] = 0.f;

    for (int k0 = 0; k0 < 192; k0 += 16) {
        {   // stage A tile transposed: thread loads (r, kk4..kk4+3), scatters
            const int r   = tid >> 2;
            const int kk4 = (tid & 3) << 2;
            const float* src = (k0 < 64)
                ? (x + (size_t)(row0 + r) * FIN + (k0 + kk4))
                : (collected + (size_t)(row0 + r) * 128 + (k0 - 64 + kk4));
            float4 v = *(const float4*)src;
            As[kk4+0][r] = v.x; As[kk4+1][r] = v.y;
            As[kk4+2][r] = v.z; As[kk4+3][r] = v.w;
        }
        #pragma unroll
        for (int rep = 0; rep < 2; ++rep) {
            const int e = (tid + rep * 256) * 4;
            const int kk = e >> 7, c = e & 127;
            *(float4*)&Bs[kk][c] = *(const float4*)(Wout + (size_t)(k0 + kk) * 128 + c);
        }
        __syncthreads();
        #pragma unroll
        for (int kk = 0; kk < 16; ++kk) {
            float4 a  = *(const float4*)&As[kk][ty * 4];
            float4 b0 = *(const float4*)&Bs[kk][tx * 4];
            float4 b1 = *(const float4*)&Bs[kk][64 + tx * 4];
            const float av[4] = {a.x, a.y, a.z, a.w};
            #pragma unroll
            for (int i = 0; i < 4; ++i) {
                acc[i][0] += av[i] * b0.x; acc[i][1] += av[i] * b0.y;
                acc[i][2] += av[i] * b0.z; acc[i][3] += av[i] * b0.w;
                acc[i][4] += av[i] * b1.x; acc[i][5] += av[i] * b1.y;
                acc[i][6] += av[i] * b1.z; acc[i][7] += av[i] * b1.w;
            }
        }
        __syncthreads();
    }

    #pragma unroll
    for (int i = 0; i < 4; ++i) {
        const int row = row0 + ty * 4 + i;
        float4 o0, o1;
        o0.x = fast_tanh(acc[i][0] + bout[tx*4+0]);
        o0.y = fast_tanh(acc[i][1] + bout[tx*4+1]);
        o0.z = fast_tanh(acc[i][2] + bout[tx*4+2]);
        o0.w = fast_tanh(acc[i][3] + bout[tx*4+3]);
        o1.x = fast_tanh(acc[i][4] + bout[64+tx*4+0]);
        o1.y = fast_tanh(acc[i][5] + bout[64+tx*4+1]);
        o1.z = fast_tanh(acc[i][6] + bout[64+tx*4+2]);
        o1.w = fast_tanh(acc[i][7] + bout[64+tx*4+3]);
        *(float4*)(out + (size_t)row * 128 + tx * 4)      = o0;
        *(float4*)(out + (size_t)row * 128 + 64 + tx * 4) = o1;
    }
}

// ---------------------------------------------------------------------------
extern "C" void kernel_launch(void* const* d_in, const int* in_sizes, int n_in,
                              void* d_out, int out_size, void* d_ws, size_t ws_size,
                              hipStream_t stream)
{
    const float* x    = (const float*)d_in[0];
    // d_in[1] = row_splits: uniform arange(B+1)*V — fixed structure, unused.
    const float* Ws   = (const float*)d_in[2];
    const float* bs   = (const float*)d_in[3];
    const float* Wf   = (const float*)d_in[4];
    const float* bf   = (const float*)d_in[5];
    const float* Wout = (const float*)d_in[6];
    const float* bout = (const float*)d_in[7];
    float* out = (float*)d_out;

    float* coords = (float*)d_ws;                                            // 1 MB
    float* feats  = (float*)((char*)d_ws + (size_t)NN * DD * sizeof(float)); // 16 MB
    float* collected = out;   // reuse d_out as scratch for pooled features

    hipLaunchKernelGGL(k_embed, dim3(NN / 64), dim3(256), 0, stream,
                       x, Ws, bs, Wf, bf, coords, feats);
    // selection: 8 rows per block (4 waves x 2 rows) -> 8192 blocks
    hipLaunchKernelGGL(k_select, dim3(NN / 8), dim3(256), 0, stream,
                       coords, collected);
    // pooling: 1 row per wave, 4 waves/block -> 16384 blocks
    hipLaunchKernelGGL(k_pool, dim3(NN / 4), dim3(256), 0, stream,
                       feats, collected);
    hipLaunchKernelGGL(k_out, dim3(NN / 64), dim3(256), 0, stream,
                       x, collected, Wout, bout, out);
}